// Round 5
// baseline (895.605 us; speedup 1.0000x reference)
//
#include <hip/hip_runtime.h>
#include <hip/hip_bf16.h>

typedef __attribute__((ext_vector_type(4))) float v4f;
typedef __attribute__((ext_vector_type(8))) short v8s;
typedef __attribute__((ext_vector_type(4))) unsigned v4u;
typedef __attribute__((ext_vector_type(2))) unsigned v2u;

// full RNE fp32->bf16 (prep kernel only)
__device__ __forceinline__ short f2bf(float f) {
  union { float f; unsigned u; } v; v.f = f;
  unsigned r = v.u + 0x7FFFu + ((v.u >> 16) & 1u);
  return (short)(r >> 16);
}
// packed 2xfp32 -> bf16x2 (RNE; v_cvt_pk_bf16_f32 where available)
__device__ __forceinline__ unsigned pk2(float a, float b) {
  union { __hip_bfloat162 h; unsigned u; } c;
  c.h = __float22bfloat162_rn(make_float2(a, b));
  return c.u;
}

// Pack W1 [128x256] and W2 [256x256] (row-major [k][n], fp32) into bf16 MFMA
// A-operand fragment order for the transposed product (W^T as A):
//   lane l of fragment (mt, kt) holds A'[n = mt*16 + (l&15)][k = kt*32 + (l>>4)*8 + j]
__global__ void pack_weights(const float* __restrict__ W1, const float* __restrict__ W2,
                             short* __restrict__ pW1, short* __restrict__ pW2) {
  int tid = blockIdx.x * 256 + threadIdx.x;
  if (tid < 32768) {
    int j = tid & 7, l = (tid >> 3) & 63, frag = tid >> 9;
    int mt = frag >> 2, kt = frag & 3;
    int n = mt * 16 + (l & 15);
    int k = kt * 32 + ((l >> 4) * 8) + j;
    pW1[tid] = f2bf(W1[k * 256 + n]);
  } else if (tid < 98304) {
    int t2 = tid - 32768;
    int j = t2 & 7, l = (t2 >> 3) & 63, frag = t2 >> 9;
    int mt = frag >> 3, kt = frag & 7;
    int n = mt * 16 + (l & 15);
    int k = kt * 32 + ((l >> 4) * 8) + j;
    pW2[t2] = f2bf(W2[k * 256 + n]);
  }
}

#define LDX_S 136   // 128 + 8 pad shorts
#define LDH_S 264   // 256 + 8 pad shorts
#define LDP_S 20    // 16 + 4 pad floats

// Fused 3-layer MLP, 256 threads = 4 waves, wave w owns hidden rows
// [w*64, w*64+64). rW2 resident in registers; rW1 re-streamed from L2 each
// tile (refreshed after last use, ~3000 cyc slack). Edge-half split keeps the
// live accumulator at 32 regs so everything fits 2 blocks/CU — two
// independent barrier domains per CU for cross-block latency hiding.
__global__ __launch_bounds__(256, 2) void mlp_v5(
    const float* __restrict__ xu, const float* __restrict__ xm,
    const void* __restrict__ eidx,
    const short* __restrict__ pW1, const short* __restrict__ pW2,
    const float* __restrict__ b1, const float* __restrict__ b2,
    const float* __restrict__ W3, const float* __restrict__ b3,
    float* __restrict__ out, int E)
{
  __shared__ __align__(16) short ldsX[64 * LDX_S];    // [edge][k0..127] bf16
  __shared__ __align__(16) short ldsH[64 * LDH_S];    // [edge][h0..255] bf16
  __shared__ __align__(16) float ldsPart[64 * LDP_S]; // [edge][wave*4+quad]

  const int t    = threadIdx.x;
  const int w    = t >> 6;        // wave 0..3 : hidden slice w*64
  const int lane = t & 63;
  const int quad = lane >> 4;
  const int lp   = lane & 15;

  const v8s* w1v = (const v8s*)pW1;
  const v8s* w2v = (const v8s*)pW2;

  // ---- resident W2 fragments (128 VGPRs, loaded once)
  v8s rW2[4][8];
#pragma unroll
  for (int mi = 0; mi < 4; ++mi)
#pragma unroll
    for (int kt = 0; kt < 8; ++kt)
      rW2[mi][kt] = w2v[(((w * 4 + mi) * 8) + kt) * 64 + lane];

  // ---- W1 fragments for the FIRST tile (streamed; refreshed every tile)
  v8s rW1[4][4];
#pragma unroll
  for (int mi = 0; mi < 4; ++mi)
#pragma unroll
    for (int kt = 0; kt < 4; ++kt)
      rW1[mi][kt] = w1v[(((w * 4 + mi) * 4) + kt) * 64 + lane];

  // ---- resident bias / W3 fragments
  v4f rb1[4], rb2[4], rw3[4];
#pragma unroll
  for (int mi = 0; mi < 4; ++mi) {
    int nh0 = w * 64 + mi * 16 + quad * 4;
    rb1[mi] = *(const v4f*)(b1 + nh0);
    rb2[mi] = *(const v4f*)(b2 + nh0);
    rw3[mi] = *(const v4f*)(W3 + nh0);
  }
  const float bias3 = b3[0];

  // ---- index dtype detection: int64 iff odd 32-bit words are all zero
  const unsigned* ew = (const unsigned*)eidx;
  unsigned oddw = (lane < 32) ? ew[2 * lane + 1] : 0u;
  const bool i64 = (__ballot(oddw != 0u) == 0ull);

  const int gi = t >> 2, gq = t & 3;   // gather: 4 threads/edge, 16 feats/side
  const int ntiles = (E + 63) >> 6;

  auto loadIdx = [&](int tl, int& row, int& col) {
    int gE = tl * 64 + gi;
    if (gE >= E || gE < 0) gE = 0;
    if (i64) {
      const long long* p = (const long long*)eidx;
      row = (int)p[gE]; col = (int)p[(long long)E + gE];
    } else {
      const int* p = (const int*)eidx;
      row = p[gE]; col = p[E + gE];
    }
  };

  unsigned gu[8], gm[8];               // packed bf16 pairs, survive to commit
  auto issueCvt = [&](int row, int col) {
    const v4f* pu = (const v4f*)(xu + (size_t)row * 64 + gq * 16);
    const v4f* pm = (const v4f*)(xm + (size_t)col * 64 + gq * 16);
    v4f U[4], M[4];
#pragma unroll
    for (int s = 0; s < 4; ++s) { U[s] = pu[s]; M[s] = pm[s]; }
#pragma unroll
    for (int s = 0; s < 4; ++s) {
      gu[2 * s]     = pk2(U[s][0], U[s][1]);
      gu[2 * s + 1] = pk2(U[s][2], U[s][3]);
      gm[2 * s]     = pk2(M[s][0], M[s][1]);
      gm[2 * s + 1] = pk2(M[s][2], M[s][3]);
    }
  };

  // prologue: idx(t0) -> feats(t0) -> idx(t1)
  int rowN, colN;
  loadIdx(blockIdx.x, rowN, colN);
  issueCvt(rowN, colN);
  loadIdx(blockIdx.x + gridDim.x, rowN, colN);

  for (int tile = blockIdx.x; tile < ntiles; tile += gridDim.x) {
    // ---- commit packed gather -> ldsX
    {
      short* px = &ldsX[gi * LDX_S + gq * 16];
      v4u a0 = { gu[0], gu[1], gu[2], gu[3] };
      v4u a1 = { gu[4], gu[5], gu[6], gu[7] };
      v4u c0 = { gm[0], gm[1], gm[2], gm[3] };
      v4u c1 = { gm[4], gm[5], gm[6], gm[7] };
      *(v4u*)(px)      = a0; *(v4u*)(px + 8)  = a1;   // user  -> k 0..63
      *(v4u*)(px + 64) = c0; *(v4u*)(px + 72) = c1;   // movie -> k 64..127
    }
    __syncthreads();                                  // B1: X visible

    // ---- layer 1 (K=128) + epilogue, by 32-edge halves (acc stays 32 regs)
#pragma unroll
    for (int h = 0; h < 2; ++h) {
      v4f acc[4][2] = {};
#pragma unroll
      for (int kt = 0; kt < 4; ++kt) {
        v8s bb[2];
#pragma unroll
        for (int n2 = 0; n2 < 2; ++n2)
          bb[n2] = *(const v8s*)&ldsX[((h * 2 + n2) * 16 + lp) * LDX_S + kt * 32 + quad * 8];
#pragma unroll
        for (int mi = 0; mi < 4; ++mi)
#pragma unroll
          for (int n2 = 0; n2 < 2; ++n2)
            acc[mi][n2] = __builtin_amdgcn_mfma_f32_16x16x32_bf16(rW1[mi][kt], bb[n2], acc[mi][n2], 0, 0, 0);
      }
#pragma unroll
      for (int mi = 0; mi < 4; ++mi) {
        int nh0 = w * 64 + mi * 16 + quad * 4;
#pragma unroll
        for (int n2 = 0; n2 < 2; ++n2) {
          int e = (h * 2 + n2) * 16 + lp;
          v4f v = acc[mi][n2] + rb1[mi];
          float x0 = v[0] > 0.f ? v[0] : 0.f;
          float x1 = v[1] > 0.f ? v[1] : 0.f;
          float x2 = v[2] > 0.f ? v[2] : 0.f;
          float x3 = v[3] > 0.f ? v[3] : 0.f;
          v2u pw; pw.x = pk2(x0, x1); pw.y = pk2(x2, x3);
          *(v2u*)&ldsH[e * LDH_S + nh0] = pw;         // ds_write_b64
        }
      }
    }
    __syncthreads();                                  // B2: H visible

    // ---- rW1 done for this tile: stream next tile's fragments (huge slack)
    if (tile + gridDim.x < ntiles) {
#pragma unroll
      for (int mi = 0; mi < 4; ++mi)
#pragma unroll
        for (int kt = 0; kt < 4; ++kt)
          rW1[mi][kt] = w1v[(((w * 4 + mi) * 4) + kt) * 64 + lane];
    }
    // ---- gather pipeline: features(t+1), indices(t+2); ~3000 cyc to commit
    issueCvt(rowN, colN);
    loadIdx(tile + 2 * gridDim.x, rowN, colN);

    // ---- layer 2 (K=256) + layer 3, by 32-edge halves
#pragma unroll
    for (int h = 0; h < 2; ++h) {
      v4f acc2[4][2] = {};
#pragma unroll
      for (int kt = 0; kt < 8; ++kt) {
        v8s bb[2];
#pragma unroll
        for (int n2 = 0; n2 < 2; ++n2)
          bb[n2] = *(const v8s*)&ldsH[((h * 2 + n2) * 16 + lp) * LDH_S + kt * 32 + quad * 8];
#pragma unroll
        for (int mi = 0; mi < 4; ++mi)
#pragma unroll
          for (int n2 = 0; n2 < 2; ++n2)
            acc2[mi][n2] = __builtin_amdgcn_mfma_f32_16x16x32_bf16(rW2[mi][kt], bb[n2], acc2[mi][n2], 0, 0, 0);
      }
      float s[2] = {0.f, 0.f};
#pragma unroll
      for (int mi = 0; mi < 4; ++mi) {
#pragma unroll
        for (int n2 = 0; n2 < 2; ++n2) {
          v4f v = acc2[mi][n2] + rb2[mi];
#pragma unroll
          for (int r = 0; r < 4; ++r) {
            float x = v[r] > 0.f ? v[r] : 0.f;
            s[n2] += x * rw3[mi][r];
          }
        }
      }
#pragma unroll
      for (int n2 = 0; n2 < 2; ++n2)
        ldsPart[((h * 2 + n2) * 16 + lp) * LDP_S + w * 4 + quad] = s[n2];
    }
    __syncthreads();                                  // B3: partials visible

    // ---- final reduce: 16 partials per edge
    if (t < 64) {
      const v4f* pp = (const v4f*)&ldsPart[t * LDP_S];
      v4f p0 = pp[0], p1 = pp[1], p2 = pp[2], p3 = pp[3];
      float r = bias3
              + (p0[0] + p0[1] + p0[2] + p0[3]) + (p1[0] + p1[1] + p1[2] + p1[3])
              + (p2[0] + p2[1] + p2[2] + p2[3]) + (p3[0] + p3[1] + p3[2] + p3[3]);
      int o = tile * 64 + t;
      if (o < E) out[o] = r;
    }
  }
}

extern "C" void kernel_launch(void* const* d_in, const int* in_sizes, int n_in,
                              void* d_out, int out_size, void* d_ws, size_t ws_size,
                              hipStream_t stream) {
  const float* xu  = (const float*)d_in[0];
  const float* xm  = (const float*)d_in[1];
  const void*  ei  = d_in[2];
  const float* W1  = (const float*)d_in[3];
  const float* b1  = (const float*)d_in[4];
  const float* W2  = (const float*)d_in[5];
  const float* b2  = (const float*)d_in[6];
  const float* W3  = (const float*)d_in[7];
  const float* b3  = (const float*)d_in[8];
  float* out = (float*)d_out;

  const int E = in_sizes[2] / 2;

  short* pW1 = (short*)d_ws;          // 64 KB
  short* pW2 = pW1 + 32768;           // 128 KB

  hipLaunchKernelGGL(pack_weights, dim3(384), dim3(256), 0, stream, W1, W2, pW1, pW2);

  const int ntiles = (E + 63) / 64;
  const int nblk = ntiles < 512 ? ntiles : 512;
  hipLaunchKernelGGL(mlp_v5, dim3(nblk), dim3(256), 0, stream,
                     xu, xm, ei, pW1, pW2, b1, b2, W3, b3, out, E);
}

// Round 6
// 538.527 us; speedup vs baseline: 1.6631x; 1.6631x over previous
//
#include <hip/hip_runtime.h>
#include <hip/hip_bf16.h>

typedef __attribute__((ext_vector_type(4))) float v4f;
typedef __attribute__((ext_vector_type(8))) short v8s;
typedef __attribute__((ext_vector_type(4))) unsigned v4u;
typedef __attribute__((ext_vector_type(2))) unsigned v2u;

// full RNE fp32->bf16 (prep kernel only)
__device__ __forceinline__ short f2bf(float f) {
  union { float f; unsigned u; } v; v.f = f;
  unsigned r = v.u + 0x7FFFu + ((v.u >> 16) & 1u);
  return (short)(r >> 16);
}
// packed 2xfp32 -> bf16x2 (RNE)
__device__ __forceinline__ unsigned pk2(float a, float b) {
  union { __hip_bfloat162 h; unsigned u; } c;
  c.h = __float22bfloat162_rn(make_float2(a, b));
  return c.u;
}

// Pack W1 [128x256] and W2 [256x256] (row-major [k][n], fp32) into bf16 MFMA
// A-operand fragment order for the transposed product (W^T as A):
//   lane l of fragment (mt, kt) holds A'[n = mt*16 + (l&15)][k = kt*32 + (l>>4)*8 + j]
__global__ void pack_weights(const float* __restrict__ W1, const float* __restrict__ W2,
                             short* __restrict__ pW1, short* __restrict__ pW2) {
  int tid = blockIdx.x * 256 + threadIdx.x;
  if (tid < 32768) {
    int j = tid & 7, l = (tid >> 3) & 63, frag = tid >> 9;
    int mt = frag >> 2, kt = frag & 3;
    int n = mt * 16 + (l & 15);
    int k = kt * 32 + ((l >> 4) * 8) + j;
    pW1[tid] = f2bf(W1[k * 256 + n]);
  } else if (tid < 98304) {
    int t2 = tid - 32768;
    int j = t2 & 7, l = (t2 >> 3) & 63, frag = t2 >> 9;
    int mt = frag >> 3, kt = frag & 7;
    int n = mt * 16 + (l & 15);
    int k = kt * 32 + ((l >> 4) * 8) + j;
    pW2[t2] = f2bf(W2[k * 256 + n]);
  }
}

// LDS layouts: power-of-2 row stride, XOR swizzle on 8-short (16 B) slots:
//   ldsX: 64 rows x 128 shorts, slot j in [0,16), phys = j ^ (row & 7)
//   ldsH: 64 rows x 256 shorts, slot j in [0,32), phys = (j&24) | ((j^(row&7))&7)
// All b128 B-reads land <=2 lanes per bank group (free per m136).

// Fused 3-layer MLP. 256 threads = 4 waves; wave w owns hidden rows
// [w*64, w*64+64). rW1 resident (64 VGPR); rW2 streamed from L2 with a 2-kt
// rolling window (32 VGPR in flight) — R5 showed 128 resident weight regs
// cannot fit the 256-reg/wave budget at 2 waves/SIMD. Biases/W3 in LDS.
__global__ __launch_bounds__(256, 2) void mlp_v6(
    const float* __restrict__ xu, const float* __restrict__ xm,
    const void* __restrict__ eidx,
    const short* __restrict__ pW1, const short* __restrict__ pW2,
    const float* __restrict__ b1, const float* __restrict__ b2,
    const float* __restrict__ W3, const float* __restrict__ b3,
    float* __restrict__ out, int E)
{
  __shared__ __align__(16) short ldsX[64 * 128];   // 16 KB, swizzled
  __shared__ __align__(16) short ldsH[64 * 256];   // 32 KB, swizzled
  __shared__ __align__(16) float ldsP[64 * 20];    // partials, padded stride
  __shared__ __align__(16) float ldsC[768];        // b1 | b2 | W3

  const int t    = threadIdx.x;
  const int w    = t >> 6;        // wave 0..3 : hidden slice w*64
  const int lane = t & 63;
  const int quad = lane >> 4;
  const int lp   = lane & 15;
  const int sw   = lp & 7;        // read-side swizzle key (row&7 == lp&7)

  // stage biases / W3 into LDS (visible after first barrier)
  ldsC[t] = b1[t]; ldsC[256 + t] = b2[t]; ldsC[512 + t] = W3[t];

  const v8s* w1v = (const v8s*)pW1;
  const v8s* w2v = (const v8s*)pW2;

  // ---- resident W1 fragments only (64 VGPRs)
  v8s rW1[4][4];
#pragma unroll
  for (int mi = 0; mi < 4; ++mi)
#pragma unroll
    for (int kt = 0; kt < 4; ++kt)
      rW1[mi][kt] = w1v[(((w * 4 + mi) * 4) + kt) * 64 + lane];

  const float bias3 = b3[0];

  // ---- index dtype detection: int64 iff odd 32-bit words are all zero
  const unsigned* ew = (const unsigned*)eidx;
  unsigned oddw = (lane < 32) ? ew[2 * lane + 1] : 0u;
  const bool i64 = (__ballot(oddw != 0u) == 0ull);

  const int gi = t >> 2, gq = t & 3;   // gather: 4 threads/edge, 16 feats/side
  const int gs = gi & 7;               // write-side swizzle key
  const int ntiles = (E + 63) >> 6;

  auto loadIdx = [&](int tl, int& row, int& col) {
    int gE = tl * 64 + gi;
    if (gE >= E || gE < 0) gE = 0;
    if (i64) {
      const long long* p = (const long long*)eidx;
      row = (int)p[gE]; col = (int)p[(long long)E + gE];
    } else {
      const int* p = (const int*)eidx;
      row = p[gE]; col = p[E + gE];
    }
  };

  v4f U[4], M[4];                      // raw features, converted only at commit
  auto issueUM = [&](int row, int col) {
    const v4f* pu = (const v4f*)(xu + (size_t)row * 64 + gq * 16);
    const v4f* pm = (const v4f*)(xm + (size_t)col * 64 + gq * 16);
#pragma unroll
    for (int s = 0; s < 4; ++s) { U[s] = pu[s]; M[s] = pm[s]; }
  };

  // prologue: idx(t0) -> feats(t0) -> idx(t1)
  int rowN, colN;
  loadIdx(blockIdx.x, rowN, colN);
  issueUM(rowN, colN);
  loadIdx(blockIdx.x + (int)gridDim.x, rowN, colN);

  for (int tile = blockIdx.x; tile < ntiles; tile += gridDim.x) {
    // ---- commit gather -> ldsX (4x ds_write_b128, swizzled slots)
    {
      short* base = &ldsX[gi * 128];
      v4u s0 = { pk2(U[0][0], U[0][1]), pk2(U[0][2], U[0][3]),
                 pk2(U[1][0], U[1][1]), pk2(U[1][2], U[1][3]) };
      v4u s1 = { pk2(U[2][0], U[2][1]), pk2(U[2][2], U[2][3]),
                 pk2(U[3][0], U[3][1]), pk2(U[3][2], U[3][3]) };
      v4u s2 = { pk2(M[0][0], M[0][1]), pk2(M[0][2], M[0][3]),
                 pk2(M[1][0], M[1][1]), pk2(M[1][2], M[1][3]) };
      v4u s3 = { pk2(M[2][0], M[2][1]), pk2(M[2][2], M[2][3]),
                 pk2(M[3][0], M[3][1]), pk2(M[3][2], M[3][3]) };
      *(v4u*)(base + (((2 * gq)     ^ gs) << 3)) = s0;  // user  k 0..63
      *(v4u*)(base + (((2 * gq + 1) ^ gs) << 3)) = s1;
      *(v4u*)(base + ((8 + ((2 * gq)     ^ gs)) << 3)) = s2;  // movie k 64..127
      *(v4u*)(base + ((8 + ((2 * gq + 1) ^ gs)) << 3)) = s3;
    }
    __syncthreads();                                  // B1: X visible

    // ---- pipeline: raw features for tile+stride, indices for tile+2*stride
    issueUM(rowN, colN);
    loadIdx(tile + 2 * (int)gridDim.x, rowN, colN);

    // ---- layer 1: K=128, rW1 resident, swizzled b128 B-reads
    v4f acc[4][4] = {};
#pragma unroll
    for (int kt = 0; kt < 4; ++kt) {
      v8s b[4];
#pragma unroll
      for (int ni = 0; ni < 4; ++ni)
        b[ni] = *(const v8s*)&ldsX[(ni * 16 + lp) * 128 + (((kt * 4 + quad) ^ sw) << 3)];
#pragma unroll
      for (int mi = 0; mi < 4; ++mi)
#pragma unroll
        for (int ni = 0; ni < 4; ++ni)
          acc[mi][ni] = __builtin_amdgcn_mfma_f32_16x16x32_bf16(rW1[mi][kt], b[ni], acc[mi][ni], 0, 0, 0);
    }

    // ---- epilogue 1: bias + relu + bf16 -> ldsH (swizzled half-slot b64)
#pragma unroll
    for (int mi = 0; mi < 4; ++mi) {
      int nh0 = w * 64 + mi * 16 + quad * 4;
      int j   = nh0 >> 3;                     // slot index 0..31
      v4f bias = *(const v4f*)&ldsC[nh0];
#pragma unroll
      for (int ni = 0; ni < 4; ++ni) {
        int e = ni * 16 + lp;
        int pj = (j & 24) | ((j ^ sw) & 7);
        v4f v = acc[mi][ni] + bias;
        float x0 = v[0] > 0.f ? v[0] : 0.f;
        float x1 = v[1] > 0.f ? v[1] : 0.f;
        float x2 = v[2] > 0.f ? v[2] : 0.f;
        float x3 = v[3] > 0.f ? v[3] : 0.f;
        v2u pw; pw.x = pk2(x0, x1); pw.y = pk2(x2, x3);
        *(v2u*)&ldsH[e * 256 + (pj << 3) + ((quad & 1) << 2)] = pw;
      }
    }
    __syncthreads();                                  // B2: H visible

    // ---- layer 2: K=256, rW2 streamed with 2-kt rolling window
    v8s a0[4], a1[4];
#pragma unroll
    for (int mi = 0; mi < 4; ++mi) a0[mi] = w2v[(((w * 4 + mi) * 8) + 0) * 64 + lane];
#pragma unroll
    for (int mi = 0; mi < 4; ++mi) a1[mi] = w2v[(((w * 4 + mi) * 8) + 1) * 64 + lane];

    v4f acc2[4][4] = {};
#pragma unroll
    for (int kt = 0; kt < 8; kt += 2) {
      v8s b[4];
#pragma unroll
      for (int ni = 0; ni < 4; ++ni)
        b[ni] = *(const v8s*)&ldsH[(ni * 16 + lp) * 256
                 + ((((kt * 4 + quad) & 24) | (((kt * 4 + quad) ^ sw) & 7)) << 3)];
#pragma unroll
      for (int mi = 0; mi < 4; ++mi)
#pragma unroll
        for (int ni = 0; ni < 4; ++ni)
          acc2[mi][ni] = __builtin_amdgcn_mfma_f32_16x16x32_bf16(a0[mi], b[ni], acc2[mi][ni], 0, 0, 0);
      if (kt < 6) {
#pragma unroll
        for (int mi = 0; mi < 4; ++mi)
          a0[mi] = w2v[(((w * 4 + mi) * 8) + kt + 2) * 64 + lane];
      }
#pragma unroll
      for (int ni = 0; ni < 4; ++ni)
        b[ni] = *(const v8s*)&ldsH[(ni * 16 + lp) * 256
                 + (((((kt + 1) * 4 + quad) & 24) | ((((kt + 1) * 4 + quad) ^ sw) & 7)) << 3)];
#pragma unroll
      for (int mi = 0; mi < 4; ++mi)
#pragma unroll
        for (int ni = 0; ni < 4; ++ni)
          acc2[mi][ni] = __builtin_amdgcn_mfma_f32_16x16x32_bf16(a1[mi], b[ni], acc2[mi][ni], 0, 0, 0);
      if (kt < 6) {
#pragma unroll
        for (int mi = 0; mi < 4; ++mi)
          a1[mi] = w2v[(((w * 4 + mi) * 8) + kt + 3) * 64 + lane];
      }
    }

    // ---- layer 3 (fp32 VALU): partial dot with W3 (from LDS)
    float s[4] = {0.f, 0.f, 0.f, 0.f};
#pragma unroll
    for (int mi = 0; mi < 4; ++mi) {
      int nh0 = w * 64 + mi * 16 + quad * 4;
      v4f bb = *(const v4f*)&ldsC[256 + nh0];
      v4f ww = *(const v4f*)&ldsC[512 + nh0];
#pragma unroll
      for (int ni = 0; ni < 4; ++ni) {
        v4f v = acc2[mi][ni] + bb;
#pragma unroll
        for (int r = 0; r < 4; ++r) {
          float x = v[r] > 0.f ? v[r] : 0.f;
          s[ni] += x * ww[r];
        }
      }
    }
#pragma unroll
    for (int ni = 0; ni < 4; ++ni)
      ldsP[(ni * 16 + lp) * 20 + w * 4 + quad] = s[ni];
    __syncthreads();                                  // B3: partials visible

    // ---- final reduce: 16 partials per edge
    if (t < 64) {
      const v4f* pp = (const v4f*)&ldsP[t * 20];
      v4f p0 = pp[0], p1 = pp[1], p2 = pp[2], p3 = pp[3];
      float r = bias3
              + (p0[0] + p0[1] + p0[2] + p0[3]) + (p1[0] + p1[1] + p1[2] + p1[3])
              + (p2[0] + p2[1] + p2[2] + p2[3]) + (p3[0] + p3[1] + p3[2] + p3[3]);
      int o = tile * 64 + t;
      if (o < E) out[o] = r;
    }
  }
}

extern "C" void kernel_launch(void* const* d_in, const int* in_sizes, int n_in,
                              void* d_out, int out_size, void* d_ws, size_t ws_size,
                              hipStream_t stream) {
  const float* xu  = (const float*)d_in[0];
  const float* xm  = (const float*)d_in[1];
  const void*  ei  = d_in[2];
  const float* W1  = (const float*)d_in[3];
  const float* b1  = (const float*)d_in[4];
  const float* W2  = (const float*)d_in[5];
  const float* b2  = (const float*)d_in[6];
  const float* W3  = (const float*)d_in[7];
  const float* b3  = (const float*)d_in[8];
  float* out = (float*)d_out;

  const int E = in_sizes[2] / 2;

  short* pW1 = (short*)d_ws;          // 64 KB
  short* pW2 = pW1 + 32768;           // 128 KB

  hipLaunchKernelGGL(pack_weights, dim3(384), dim3(256), 0, stream, W1, W2, pW1, pW2);

  const int ntiles = (E + 63) / 64;
  const int nblk = ntiles < 512 ? ntiles : 512;
  hipLaunchKernelGGL(mlp_v6, dim3(nblk), dim3(256), 0, stream,
                     xu, xm, ei, pW1, pW2, b1, b2, W3, b3, out, E);
}

// Round 7
// 272.930 us; speedup vs baseline: 3.2815x; 1.9731x over previous
//
#include <hip/hip_runtime.h>
#include <hip/hip_bf16.h>

typedef __attribute__((ext_vector_type(4))) float v4f;
typedef __attribute__((ext_vector_type(8))) short v8s;
typedef __attribute__((ext_vector_type(4))) unsigned v4u;
typedef __attribute__((ext_vector_type(2))) unsigned v2u;

// full RNE fp32->bf16 (prep kernel only)
__device__ __forceinline__ short f2bf(float f) {
  union { float f; unsigned u; } v; v.f = f;
  unsigned r = v.u + 0x7FFFu + ((v.u >> 16) & 1u);
  return (short)(r >> 16);
}
// packed 2xfp32 -> bf16x2, single v_cvt_pk_bf16_f32
__device__ __forceinline__ unsigned pk2(float a, float b) {
  union { __hip_bfloat162 h; unsigned u; } c;
  c.h = __float22bfloat162_rn(make_float2(a, b));
  return c.u;
}

// Pack W1 [128x256] and W2 [256x256] (row-major [k][n], fp32) into bf16 MFMA
// A-operand fragment order for the transposed product (W^T as A):
//   lane l of fragment (mt, kt) holds A'[n = mt*16 + (l&15)][k = kt*32 + (l>>4)*8 + j]
__global__ void pack_weights(const float* __restrict__ W1, const float* __restrict__ W2,
                             short* __restrict__ pW1, short* __restrict__ pW2) {
  int tid = blockIdx.x * 256 + threadIdx.x;
  if (tid < 32768) {
    int j = tid & 7, l = (tid >> 3) & 63, frag = tid >> 9;
    int mt = frag >> 2, kt = frag & 3;
    int n = mt * 16 + (l & 15);
    int k = kt * 32 + ((l >> 4) * 8) + j;
    pW1[tid] = f2bf(W1[k * 256 + n]);
  } else if (tid < 98304) {
    int t2 = tid - 32768;
    int j = t2 & 7, l = (t2 >> 3) & 63, frag = t2 >> 9;
    int mt = frag >> 3, kt = frag & 7;
    int n = mt * 16 + (l & 15);
    int k = kt * 32 + ((l >> 4) * 8) + j;
    pW2[t2] = f2bf(W2[k * 256 + n]);
  }
}

#define LDX_S 136   // 128 + 8 pad shorts (proven 2-way-max in R4)
#define LDH_S 264   // 256 + 8 pad shorts
#define LDP_S 36    // 32 + 4 pad floats

// Persistent fused 3-layer MLP — R4 structure (the only allocator-feasible
// one: 8 waves x 32 hidden rows, 96 resident weight VGPRs, VGPR_Count=108,
// no spill). R7 changes: pk2 packs, bias-init accumulators, 2 barriers/tile
// (deferred partial-reduce rides the next tile's B1).
__global__ __launch_bounds__(512, 2) void mlp_v7(
    const float* __restrict__ xu, const float* __restrict__ xm,
    const void* __restrict__ eidx,
    const short* __restrict__ pW1, const short* __restrict__ pW2,
    const float* __restrict__ b1, const float* __restrict__ b2,
    const float* __restrict__ W3, const float* __restrict__ b3,
    float* __restrict__ out, int E)
{
  __shared__ __align__(16) short ldsX[64 * LDX_S];   // [edge][k0..127] bf16
  __shared__ __align__(16) short ldsH[64 * LDH_S];   // [edge][h0..255] bf16
  __shared__ __align__(16) float ldsPart[64 * LDP_S];// [edge][slot0..31]

  const int t    = threadIdx.x;
  const int w    = t >> 6;        // wave 0..7 : hidden slice w*32
  const int lane = t & 63;
  const int quad = lane >> 4;
  const int lp   = lane & 15;

  // ---- resident weight fragments (96 VGPRs/wave, loaded once)
  const v8s* w1v = (const v8s*)pW1;
  const v8s* w2v = (const v8s*)pW2;
  v8s rW1[2][4], rW2[2][8];
#pragma unroll
  for (int mi = 0; mi < 2; ++mi)
#pragma unroll
    for (int kt = 0; kt < 4; ++kt)
      rW1[mi][kt] = w1v[(((w * 2 + mi) * 4) + kt) * 64 + lane];
#pragma unroll
  for (int mi = 0; mi < 2; ++mi)
#pragma unroll
    for (int kt = 0; kt < 8; ++kt)
      rW2[mi][kt] = w2v[(((w * 2 + mi) * 8) + kt) * 64 + lane];

  // ---- resident bias / W3 fragments (match C-layout rows n = quad*4+r)
  v4f rb1[2], rb2[2], rw3[2];
#pragma unroll
  for (int mi = 0; mi < 2; ++mi) {
    int nh0 = w * 32 + mi * 16 + quad * 4;
    rb1[mi] = *(const v4f*)(b1 + nh0);
    rb2[mi] = *(const v4f*)(b2 + nh0);
    rw3[mi] = *(const v4f*)(W3 + nh0);
  }
  const float bias3 = b3[0];

  // ---- index dtype detection: int64 iff odd 32-bit words are all zero
  const unsigned* ew = (const unsigned*)eidx;
  unsigned oddw = (lane < 32) ? ew[2 * lane + 1] : 0u;
  const bool i64 = (__ballot(oddw != 0u) == 0ull);

  const int gi = t >> 3, gq = t & 7;   // gather: 8 threads/edge, 8 feats/side
  const int ntiles = (E + 63) >> 6;

  auto loadIdx = [&](int tl, int& row, int& col) {
    int gE = tl * 64 + gi;
    if (gE >= E || gE < 0) gE = 0;
    if (i64) {
      const long long* p = (const long long*)eidx;
      row = (int)p[gE]; col = (int)p[(long long)E + gE];
    } else {
      const int* p = (const int*)eidx;
      row = p[gE]; col = p[E + gE];
    }
  };

  v4f U0, U1, M0, M1;
  auto issueUM = [&](int row, int col) {
    const v4f* pu = (const v4f*)(xu + (size_t)row * 64 + gq * 8);
    const v4f* pm = (const v4f*)(xm + (size_t)col * 64 + gq * 8);
    U0 = pu[0]; U1 = pu[1]; M0 = pm[0]; M1 = pm[1];
  };

  // prologue: idx(t0) -> feats(t0) -> idx(t0+stride)
  int rowN, colN;
  loadIdx(blockIdx.x, rowN, colN);
  issueUM(rowN, colN);
  loadIdx(blockIdx.x + (int)gridDim.x, rowN, colN);

  int prev = -1;                       // tile whose partials await reduction
  for (int tile = blockIdx.x; tile < ntiles; tile += gridDim.x) {
    // ---- commit prefetched gather -> ldsX (pk2: 8 cvt-pk per thread)
    {
      short* px = &ldsX[gi * LDX_S + gq * 8];
      v4u a = { pk2(U0[0], U0[1]), pk2(U0[2], U0[3]),
                pk2(U1[0], U1[1]), pk2(U1[2], U1[3]) };
      v4u c = { pk2(M0[0], M0[1]), pk2(M0[2], M0[3]),
                pk2(M1[0], M1[1]), pk2(M1[2], M1[3]) };
      *(v4u*)(px)      = a;     // user  -> k 0..63
      *(v4u*)(px + 64) = c;     // movie -> k 64..127
    }
    __syncthreads();                        // B1: X(tile) AND Part(prev) visible

    // ---- pipeline: features for tile+stride, indices for tile+2*stride
    issueUM(rowN, colN);
    loadIdx(tile + 2 * (int)gridDim.x, rowN, colN);

    // ---- deferred reduce of previous tile's partials (B2 below orders this
    //      read before this tile's partial writes)
    if (prev >= 0 && t < 64) {
      const v4f* pp = (const v4f*)&ldsPart[t * LDP_S];
      float r = bias3;
#pragma unroll
      for (int c = 0; c < 8; ++c) {
        v4f p = pp[c];
        r += (p[0] + p[1]) + (p[2] + p[3]);
      }
      int o = prev * 64 + t;
      if (o < E) out[o] = r;
    }

    // ---- layer 1: K=128, weights resident, acc pre-loaded with b1
    v4f acc[2][4];
#pragma unroll
    for (int mi = 0; mi < 2; ++mi)
#pragma unroll
      for (int ni = 0; ni < 4; ++ni)
        acc[mi][ni] = rb1[mi];
#pragma unroll
    for (int kt = 0; kt < 4; ++kt) {
      v8s b[4];
#pragma unroll
      for (int ni = 0; ni < 4; ++ni)
        b[ni] = *(const v8s*)&ldsX[(ni * 16 + lp) * LDX_S + kt * 32 + quad * 8];
#pragma unroll
      for (int mi = 0; mi < 2; ++mi)
#pragma unroll
        for (int ni = 0; ni < 4; ++ni)
          acc[mi][ni] = __builtin_amdgcn_mfma_f32_16x16x32_bf16(rW1[mi][kt], b[ni], acc[mi][ni], 0, 0, 0);
    }

    // ---- epilogue 1: relu + pk2 -> ldsH[e][n]   (bias already in acc)
#pragma unroll
    for (int mi = 0; mi < 2; ++mi) {
      int nh0 = w * 32 + mi * 16 + quad * 4;
#pragma unroll
      for (int ni = 0; ni < 4; ++ni) {
        int e = ni * 16 + lp;
        v4f v = acc[mi][ni];
        float x0 = fmaxf(v[0], 0.f);
        float x1 = fmaxf(v[1], 0.f);
        float x2 = fmaxf(v[2], 0.f);
        float x3 = fmaxf(v[3], 0.f);
        v2u pw; pw.x = pk2(x0, x1); pw.y = pk2(x2, x3);
        *(v2u*)&ldsH[e * LDH_S + nh0] = pw;           // ds_write_b64
      }
    }
    __syncthreads();                        // B2: H visible; reduce-before-P order

    // ---- layer 2: K=256, weights resident, acc2 pre-loaded with b2
    v4f acc2[2][4];
#pragma unroll
    for (int mi = 0; mi < 2; ++mi)
#pragma unroll
      for (int ni = 0; ni < 4; ++ni)
        acc2[mi][ni] = rb2[mi];
#pragma unroll
    for (int kt = 0; kt < 8; ++kt) {
      v8s b[4];
#pragma unroll
      for (int ni = 0; ni < 4; ++ni)
        b[ni] = *(const v8s*)&ldsH[(ni * 16 + lp) * LDH_S + kt * 32 + quad * 8];
#pragma unroll
      for (int mi = 0; mi < 2; ++mi)
#pragma unroll
        for (int ni = 0; ni < 4; ++ni)
          acc2[mi][ni] = __builtin_amdgcn_mfma_f32_16x16x32_bf16(rW2[mi][kt], b[ni], acc2[mi][ni], 0, 0, 0);
    }

    // ---- layer 3 (fp32 VALU): partial dot with W3 (bias already in acc2)
    float s[4] = {0.f, 0.f, 0.f, 0.f};
#pragma unroll
    for (int mi = 0; mi < 2; ++mi) {
#pragma unroll
      for (int ni = 0; ni < 4; ++ni) {
        v4f v = acc2[mi][ni];
#pragma unroll
        for (int r = 0; r < 4; ++r)
          s[ni] += fmaxf(v[r], 0.f) * rw3[mi][r];
      }
    }
#pragma unroll
    for (int ni = 0; ni < 4; ++ni)
      ldsPart[(ni * 16 + lp) * LDP_S + w * 4 + quad] = s[ni];
    // no barrier here — next iteration's B1 publishes the partials
    prev = tile;
  }

  // ---- drain: reduce the final tile's partials
  if (prev >= 0) {
    __syncthreads();
    if (t < 64) {
      const v4f* pp = (const v4f*)&ldsPart[t * LDP_S];
      float r = bias3;
#pragma unroll
      for (int c = 0; c < 8; ++c) {
        v4f p = pp[c];
        r += (p[0] + p[1]) + (p[2] + p[3]);
      }
      int o = prev * 64 + t;
      if (o < E) out[o] = r;
    }
  }
}

extern "C" void kernel_launch(void* const* d_in, const int* in_sizes, int n_in,
                              void* d_out, int out_size, void* d_ws, size_t ws_size,
                              hipStream_t stream) {
  const float* xu  = (const float*)d_in[0];
  const float* xm  = (const float*)d_in[1];
  const void*  ei  = d_in[2];
  const float* W1  = (const float*)d_in[3];
  const float* b1  = (const float*)d_in[4];
  const float* W2  = (const float*)d_in[5];
  const float* b2  = (const float*)d_in[6];
  const float* W3  = (const float*)d_in[7];
  const float* b3  = (const float*)d_in[8];
  float* out = (float*)d_out;

  const int E = in_sizes[2] / 2;

  short* pW1 = (short*)d_ws;          // 64 KB
  short* pW2 = pW1 + 32768;           // 128 KB

  hipLaunchKernelGGL(pack_weights, dim3(384), dim3(256), 0, stream, W1, W2, pW1, pW2);

  const int ntiles = (E + 63) / 64;
  const int nblk = ntiles < 256 ? ntiles : 256;
  hipLaunchKernelGGL(mlp_v7, dim3(nblk), dim3(512), 0, stream,
                     xu, xm, ei, pW1, pW2, b1, b2, W3, b3, out, E);
}

// Round 8
// 265.395 us; speedup vs baseline: 3.3746x; 1.0284x over previous
//
#include <hip/hip_runtime.h>
#include <hip/hip_bf16.h>

typedef __attribute__((ext_vector_type(4))) float v4f;
typedef __attribute__((ext_vector_type(8))) short v8s;
typedef __attribute__((ext_vector_type(4))) unsigned v4u;
typedef __attribute__((ext_vector_type(2))) unsigned v2u;

// full RNE fp32->bf16 (prep kernel only)
__device__ __forceinline__ short f2bf(float f) {
  union { float f; unsigned u; } v; v.f = f;
  unsigned r = v.u + 0x7FFFu + ((v.u >> 16) & 1u);
  return (short)(r >> 16);
}
// packed 2xfp32 -> bf16x2, single v_cvt_pk_bf16_f32
__device__ __forceinline__ unsigned pk2(float a, float b) {
  union { __hip_bfloat162 h; unsigned u; } c;
  c.h = __float22bfloat162_rn(make_float2(a, b));
  return c.u;
}

// Pack W1 [128x256] and W2 [256x256] (row-major [k][n], fp32) into bf16 MFMA
// A-operand fragment order for the transposed product (W^T as A):
//   lane l of fragment (mt, kt) holds A'[n = mt*16 + (l&15)][k = kt*32 + (l>>4)*8 + j]
__global__ void pack_weights(const float* __restrict__ W1, const float* __restrict__ W2,
                             short* __restrict__ pW1, short* __restrict__ pW2) {
  int tid = blockIdx.x * 256 + threadIdx.x;
  if (tid < 32768) {
    int j = tid & 7, l = (tid >> 3) & 63, frag = tid >> 9;
    int mt = frag >> 2, kt = frag & 3;
    int n = mt * 16 + (l & 15);
    int k = kt * 32 + ((l >> 4) * 8) + j;
    pW1[tid] = f2bf(W1[k * 256 + n]);
  } else if (tid < 98304) {
    int t2 = tid - 32768;
    int j = t2 & 7, l = (t2 >> 3) & 63, frag = t2 >> 9;
    int mt = frag >> 3, kt = frag & 7;
    int n = mt * 16 + (l & 15);
    int k = kt * 32 + ((l >> 4) * 8) + j;
    pW2[t2] = f2bf(W2[k * 256 + n]);
  }
}

#define LDX_S 136   // 128 + 8 pad shorts
#define LDH_S 264   // 256 + 8 pad shorts
#define LDP_S 36    // 32 + 4 pad floats
#define XBUF (64 * LDX_S)   // 8704 shorts / buffer
#define HBUF (64 * LDH_S)   // 16896 shorts / buffer
#define PBUF (64 * LDP_S)   // 2304 floats / buffer
#define SMEM_BYTES (2*XBUF*2 + 2*HBUF*2 + 2*PBUF*4)   // 120832

// Single-barrier 3-deep pipelined fused MLP. 512 threads = 8 waves, wave w
// owns hidden rows [w*32, w*32+32) (96 resident weight VGPRs — the proven
// allocator-feasible split). Phase k (one __syncthreads each):
//   commit X(t_k) | layer1 X(t_{k-1})->H | layer2+3 H(t_{k-2})->P | store P(t_{k-3})
// All four stages are independent, so layer-2's LDS read burst overlaps
// layer-1's MFMAs inside the phase instead of serializing behind barriers.
// X/H/P double-buffered: 118 KB dynamic LDS -> 1 block/CU.
__global__ __launch_bounds__(512, 2) void mlp_v8(
    const float* __restrict__ xu, const float* __restrict__ xm,
    const void* __restrict__ eidx,
    const short* __restrict__ pW1, const short* __restrict__ pW2,
    const float* __restrict__ b1, const float* __restrict__ b2,
    const float* __restrict__ W3, const float* __restrict__ b3,
    float* __restrict__ out, int E)
{
  extern __shared__ __align__(16) char smem[];
  short* ldsX = (short*)smem;                       // [2][XBUF]
  short* ldsH = (short*)(smem + 2 * XBUF * 2);      // [2][HBUF]
  float* ldsP = (float*)(smem + 2 * XBUF * 2 + 2 * HBUF * 2); // [2][PBUF]

  const int t    = threadIdx.x;
  const int w    = t >> 6;        // wave 0..7 : hidden slice w*32
  const int lane = t & 63;
  const int quad = lane >> 4;
  const int lp   = lane & 15;

  // ---- resident weight fragments (96 VGPRs/wave, loaded once)
  const v8s* w1v = (const v8s*)pW1;
  const v8s* w2v = (const v8s*)pW2;
  v8s rW1[2][4], rW2[2][8];
#pragma unroll
  for (int mi = 0; mi < 2; ++mi)
#pragma unroll
    for (int kt = 0; kt < 4; ++kt)
      rW1[mi][kt] = w1v[(((w * 2 + mi) * 4) + kt) * 64 + lane];
#pragma unroll
  for (int mi = 0; mi < 2; ++mi)
#pragma unroll
    for (int kt = 0; kt < 8; ++kt)
      rW2[mi][kt] = w2v[(((w * 2 + mi) * 8) + kt) * 64 + lane];

  // ---- resident bias / W3 fragments
  v4f rb1[2], rb2[2], rw3[2];
#pragma unroll
  for (int mi = 0; mi < 2; ++mi) {
    int nh0 = w * 32 + mi * 16 + quad * 4;
    rb1[mi] = *(const v4f*)(b1 + nh0);
    rb2[mi] = *(const v4f*)(b2 + nh0);
    rw3[mi] = *(const v4f*)(W3 + nh0);
  }
  const float bias3 = b3[0];

  // ---- index dtype detection: int64 iff odd 32-bit words are all zero
  const unsigned* ew = (const unsigned*)eidx;
  unsigned oddw = (lane < 32) ? ew[2 * lane + 1] : 0u;
  const bool i64 = (__ballot(oddw != 0u) == 0ull);

  const int gi = t >> 3, gq = t & 7;   // gather: 8 threads/edge, 8 feats/side
  const int ntiles = (E + 63) >> 6;
  const int S   = (int)gridDim.x;
  const int bid = (int)blockIdx.x;
  const int Tb  = (ntiles - bid + S - 1) / S;   // tiles this block owns (>=1)

  auto loadIdx = [&](int tl, int& row, int& col) {
    int gE = tl * 64 + gi;
    if (gE >= E || gE < 0) gE = 0;
    if (i64) {
      const long long* p = (const long long*)eidx;
      row = (int)p[gE]; col = (int)p[(long long)E + gE];
    } else {
      const int* p = (const int*)eidx;
      row = p[gE]; col = p[E + gE];
    }
  };

  v4f U0, U1, M0, M1;
  auto issueUM = [&](int row, int col) {
    const v4f* pu = (const v4f*)(xu + (size_t)row * 64 + gq * 8);
    const v4f* pm = (const v4f*)(xm + (size_t)col * 64 + gq * 8);
    U0 = pu[0]; U1 = pu[1]; M0 = pm[0]; M1 = pm[1];
  };

  // prologue: idx(t0) -> feats(t0) -> idx(t1)
  int rowN, colN;
  loadIdx(bid, rowN, colN);
  issueUM(rowN, colN);
  loadIdx(bid + S, rowN, colN);

  for (int k = 0; k <= Tb + 2; ++k) {
    __syncthreads();                 // publishes ALL of phase k-1's LDS writes
    const int pb = k & 1;
    const int tg = bid + k * S;      // tile being gather-committed this phase

    // ---- stage G: commit prefetched features -> ldsX[pb]
    if (k < Tb) {
      short* px = &ldsX[pb * XBUF + gi * LDX_S + gq * 8];
      v4u a = { pk2(U0[0], U0[1]), pk2(U0[2], U0[3]),
                pk2(U1[0], U1[1]), pk2(U1[2], U1[3]) };
      v4u c = { pk2(M0[0], M0[1]), pk2(M0[2], M0[3]),
                pk2(M1[0], M1[1]), pk2(M1[2], M1[3]) };
      *(v4u*)(px)      = a;     // user  -> k 0..63
      *(v4u*)(px + 64) = c;     // movie -> k 64..127
    }
    // ---- prefetch: features(t_{k+1}), indices(t_{k+2})
    if (k + 1 < Tb) {
      issueUM(rowN, colN);
      loadIdx(tg + 2 * S, rowN, colN);
    }

    // ---- stage R: reduce + store tile t3 = tg - 3S from ldsP[pb^1]
    const int t3 = tg - 3 * S;
    if (t3 >= 0 && t < 64) {
      const v4f* pp = (const v4f*)&ldsP[(pb ^ 1) * PBUF + t * LDP_S];
      float r = bias3;
#pragma unroll
      for (int c = 0; c < 8; ++c) {
        v4f p = pp[c];
        r += (p[0] + p[1]) + (p[2] + p[3]);
      }
      int o = t3 * 64 + t;
      if (o < E) out[o] = r;
    }

    // ---- stage L1: layer 1 of t1 = tg - S : ldsX[pb^1] -> ldsH[pb^1]
    const int t1 = tg - S;
    if (t1 >= 0 && t1 < ntiles) {
      v4f acc[2][4];
#pragma unroll
      for (int mi = 0; mi < 2; ++mi)
#pragma unroll
        for (int ni = 0; ni < 4; ++ni)
          acc[mi][ni] = rb1[mi];
#pragma unroll
      for (int kt = 0; kt < 4; ++kt) {
        v8s b[4];
#pragma unroll
        for (int ni = 0; ni < 4; ++ni)
          b[ni] = *(const v8s*)&ldsX[(pb ^ 1) * XBUF + (ni * 16 + lp) * LDX_S + kt * 32 + quad * 8];
#pragma unroll
        for (int mi = 0; mi < 2; ++mi)
#pragma unroll
          for (int ni = 0; ni < 4; ++ni)
            acc[mi][ni] = __builtin_amdgcn_mfma_f32_16x16x32_bf16(rW1[mi][kt], b[ni], acc[mi][ni], 0, 0, 0);
      }
#pragma unroll
      for (int mi = 0; mi < 2; ++mi) {
        int nh0 = w * 32 + mi * 16 + quad * 4;
#pragma unroll
        for (int ni = 0; ni < 4; ++ni) {
          int e = ni * 16 + lp;
          v4f v = acc[mi][ni];
          v2u pw; pw.x = pk2(fmaxf(v[0], 0.f), fmaxf(v[1], 0.f));
          pw.y = pk2(fmaxf(v[2], 0.f), fmaxf(v[3], 0.f));
          *(v2u*)&ldsH[(pb ^ 1) * HBUF + e * LDH_S + nh0] = pw;   // ds_write_b64
        }
      }
    }

    // ---- stage L2: layer 2+3 of t2 = tg - 2S : ldsH[pb] -> ldsP[pb]
    const int t2 = tg - 2 * S;
    if (t2 >= 0 && t2 < ntiles) {
      v4f acc2[2][4];
#pragma unroll
      for (int mi = 0; mi < 2; ++mi)
#pragma unroll
        for (int ni = 0; ni < 4; ++ni)
          acc2[mi][ni] = rb2[mi];
#pragma unroll
      for (int kt = 0; kt < 8; ++kt) {
        v8s b[4];
#pragma unroll
        for (int ni = 0; ni < 4; ++ni)
          b[ni] = *(const v8s*)&ldsH[pb * HBUF + (ni * 16 + lp) * LDH_S + kt * 32 + quad * 8];
#pragma unroll
        for (int mi = 0; mi < 2; ++mi)
#pragma unroll
          for (int ni = 0; ni < 4; ++ni)
            acc2[mi][ni] = __builtin_amdgcn_mfma_f32_16x16x32_bf16(rW2[mi][kt], b[ni], acc2[mi][ni], 0, 0, 0);
      }
      float s[4] = {0.f, 0.f, 0.f, 0.f};
#pragma unroll
      for (int mi = 0; mi < 2; ++mi) {
#pragma unroll
        for (int ni = 0; ni < 4; ++ni) {
          v4f v = acc2[mi][ni];
#pragma unroll
          for (int r = 0; r < 4; ++r)
            s[ni] += fmaxf(v[r], 0.f) * rw3[mi][r];
        }
      }
#pragma unroll
      for (int ni = 0; ni < 4; ++ni)
        ldsP[pb * PBUF + (ni * 16 + lp) * LDP_S + w * 4 + quad] = s[ni];
    }
  }
}

extern "C" void kernel_launch(void* const* d_in, const int* in_sizes, int n_in,
                              void* d_out, int out_size, void* d_ws, size_t ws_size,
                              hipStream_t stream) {
  const float* xu  = (const float*)d_in[0];
  const float* xm  = (const float*)d_in[1];
  const void*  ei  = d_in[2];
  const float* W1  = (const float*)d_in[3];
  const float* b1  = (const float*)d_in[4];
  const float* W2  = (const float*)d_in[5];
  const float* b2  = (const float*)d_in[6];
  const float* W3  = (const float*)d_in[7];
  const float* b3  = (const float*)d_in[8];
  float* out = (float*)d_out;

  const int E = in_sizes[2] / 2;

  short* pW1 = (short*)d_ws;          // 64 KB
  short* pW2 = pW1 + 32768;           // 128 KB

  hipLaunchKernelGGL(pack_weights, dim3(384), dim3(256), 0, stream, W1, W2, pW1, pW2);

  // 118 KB dynamic LDS (> 64 KB static limit); idempotent, graph-capture-safe
  hipFuncSetAttribute((const void*)mlp_v8,
                      hipFuncAttributeMaxDynamicSharedMemorySize, SMEM_BYTES);

  const int ntiles = (E + 63) / 64;
  const int nblk = ntiles < 256 ? ntiles : 256;
  hipLaunchKernelGGL(mlp_v8, dim3(nblk), dim3(512), SMEM_BYTES, stream,
                     xu, xm, ei, pW1, pW2, b1, b2, W3, b3, out, E);
}